// Round 1
// baseline (107.727 us; speedup 1.0000x reference)
//
#include <hip/hip_runtime.h>
#include <hip/hip_bf16.h>

// Causal flash-attention forward. B=4, L=2048, H=8, E=64, fp32 in/out.
// Layout: [B, L, H, E] -> ((b*L + l)*H + h)*E + e ; row stride H*E = 512 floats.

#define Bc 4
#define Lc 2048
#define Hc 8
#define Ec 64
#define QBLK 64
#define KVBLK 64

using f32x4  = __attribute__((ext_vector_type(4))) float;
using bf16x8 = __attribute__((ext_vector_type(8))) short;

__device__ __forceinline__ unsigned short f2bf(float f) {
    unsigned int u = __float_as_uint(f);
    u += 0x7FFFu + ((u >> 16) & 1u);   // round-to-nearest-even
    return (unsigned short)(u >> 16);
}

__global__ __launch_bounds__(256)
void fa_fwd_kernel(const float* __restrict__ Q, const float* __restrict__ K,
                   const float* __restrict__ V, float* __restrict__ Out)
{
    // LDS: K tile [64][64] bf16 (XOR-swizzled rows), Vt tile [e=64][kv=64] bf16
    // (XOR-swizzled), P per-wave [16][64] bf16 (XOR-swizzled).
    __shared__ unsigned int K_lds[KVBLK * Ec / 2];   // 8 KB
    __shared__ unsigned int Vt_lds[Ec * KVBLK / 2];  // 8 KB
    __shared__ unsigned short P_lds[4 * 16 * KVBLK]; // 8 KB

    const int bid = blockIdx.x;
    const int qi  = bid >> 5;        // 0..31
    const int bh  = bid & 31;
    const int b   = bh >> 3, h = bh & 7;
    const int qt  = (Lc / QBLK - 1) - qi;   // longest-running tiles first
    const int qbase = qt * QBLK;

    const int tid  = threadIdx.x;
    const int wid  = tid >> 6;
    const int lane = tid & 63;
    const int l15  = lane & 15;
    const int l4   = lane >> 4;

    const size_t base_bh = (size_t)b * Lc * Hc * Ec + (size_t)h * Ec;
    const int strideL = Hc * Ec; // 512

    // ---- Q fragments (held in registers for the whole kernel) ----
    const int qrow0 = qbase + 16 * wid;
    bf16x8 qa[2];
    {
        const float* qpr = Q + base_bh + (size_t)(qrow0 + l15) * strideL;
        #pragma unroll
        for (int kc = 0; kc < 2; ++kc) {
            const float* p = qpr + 32 * kc + 8 * l4;
            float4 f0 = *(const float4*)(p);
            float4 f1 = *(const float4*)(p + 4);
            union { bf16x8 v; unsigned short u[8]; } pk;
            pk.u[0] = f2bf(f0.x); pk.u[1] = f2bf(f0.y);
            pk.u[2] = f2bf(f0.z); pk.u[3] = f2bf(f0.w);
            pk.u[4] = f2bf(f1.x); pk.u[5] = f2bf(f1.y);
            pk.u[6] = f2bf(f1.z); pk.u[7] = f2bf(f1.w);
            qa[kc] = pk.v;
        }
    }

    f32x4 o[4] = {};                       // O acc: e-chunks c=0..3
    float m_run[4], l_run[4];
    #pragma unroll
    for (int r = 0; r < 4; ++r) { m_run[r] = -1e30f; l_run[r] = 0.f; }

    const float SL2E = 0.125f * 1.44269504088896340736f; // scale * log2(e)

    char* kb_base = (char*)K_lds;
    char* vt_base = (char*)Vt_lds;
    char* pwb = (char*)(P_lds + wid * 16 * KVBLK);

    for (int kt = 0; kt <= qt; ++kt) {
        const int kbase = kt * KVBLK;
        __syncthreads();   // previous tile's compute done before overwrite

        // ---- stage K (row-major, swizzled) and V (transposed, swizzled) ----
        {
            const int r = tid >> 2, quad = tid & 3;
            const int c0 = 16 * quad;
            const float* kp = K + base_bh + (size_t)(kbase + r) * strideL + c0;
            const float* vp = V + base_bh + (size_t)(kbase + r) * strideL + c0;
            float4 kf[4], vf[4];
            #pragma unroll
            for (int i = 0; i < 4; ++i) { kf[i] = *(const float4*)(kp + 4 * i); }
            #pragma unroll
            for (int i = 0; i < 4; ++i) { vf[i] = *(const float4*)(vp + 4 * i); }

            unsigned int kw[8];
            #pragma unroll
            for (int i = 0; i < 4; ++i) {
                kw[2*i]   = (unsigned)f2bf(kf[i].x) | ((unsigned)f2bf(kf[i].y) << 16);
                kw[2*i+1] = (unsigned)f2bf(kf[i].z) | ((unsigned)f2bf(kf[i].w) << 16);
            }
            const int rswz = (r & 7) << 4;
            *(uint4*)(kb_base + r * 128 + (((2 * c0))      ^ rswz)) = *(uint4*)&kw[0];
            *(uint4*)(kb_base + r * 128 + (((2 * c0 + 16)) ^ rswz)) = *(uint4*)&kw[4];

            const float* vff = (const float*)vf;
            #pragma unroll
            for (int i = 0; i < 16; ++i) {
                const int c = c0 + i;          // e index
                // Vt[e=c][kv=r]
                *(unsigned short*)(vt_base + c * 128 + ((2 * r) ^ ((c & 7) << 4))) = f2bf(vff[i]);
            }
        }
        __syncthreads();

        // ---- S = Q K^T : 4 kv-chunks of 16, K split in two 32-wide halves ----
        f32x4 s[4];
        #pragma unroll
        for (int n = 0; n < 4; ++n) {
            const int row = 16 * n + l15;
            const int rs = (row & 7) << 4;
            bf16x8 b0 = *(const bf16x8*)(kb_base + row * 128 + ((16 * l4)      ^ rs));
            bf16x8 b1 = *(const bf16x8*)(kb_base + row * 128 + ((64 + 16 * l4) ^ rs));
            f32x4 acc = {0.f, 0.f, 0.f, 0.f};
            acc = __builtin_amdgcn_mfma_f32_16x16x32_bf16(qa[0], b0, acc, 0, 0, 0);
            acc = __builtin_amdgcn_mfma_f32_16x16x32_bf16(qa[1], b1, acc, 0, 0, 0);
            s[n] = acc;
        }

        // ---- causal mask (diagonal tile only) ----
        if (kt == qt) {
            #pragma unroll
            for (int n = 0; n < 4; ++n) {
                const int kv_g = kbase + 16 * n + l15;
                #pragma unroll
                for (int r = 0; r < 4; ++r) {
                    const int q_g = qrow0 + 4 * l4 + r;
                    if (kv_g > q_g) s[n][r] = -1e30f;
                }
            }
        }

        // ---- online softmax ----
        float pmax[4];
        #pragma unroll
        for (int r = 0; r < 4; ++r)
            pmax[r] = fmaxf(fmaxf(s[0][r], s[1][r]), fmaxf(s[2][r], s[3][r]));
        #pragma unroll
        for (int mm = 1; mm <= 8; mm <<= 1) {
            #pragma unroll
            for (int r = 0; r < 4; ++r)
                pmax[r] = fmaxf(pmax[r], __shfl_xor(pmax[r], mm, 64));
        }
        float fac[4], m_new[4];
        #pragma unroll
        for (int r = 0; r < 4; ++r) {
            m_new[r] = fmaxf(m_run[r], pmax[r]);
            fac[r] = __builtin_exp2f((m_run[r] - m_new[r]) * SL2E);
            m_run[r] = m_new[r];
        }
        float ps[4] = {0.f, 0.f, 0.f, 0.f};
        unsigned short pb[4][4];
        #pragma unroll
        for (int n = 0; n < 4; ++n) {
            #pragma unroll
            for (int r = 0; r < 4; ++r) {
                const float p = __builtin_exp2f((s[n][r] - m_new[r]) * SL2E);
                ps[r] += p;
                pb[n][r] = f2bf(p);
            }
        }
        #pragma unroll
        for (int mm = 1; mm <= 8; mm <<= 1) {
            #pragma unroll
            for (int r = 0; r < 4; ++r)
                ps[r] += __shfl_xor(ps[r], mm, 64);
        }
        #pragma unroll
        for (int r = 0; r < 4; ++r) l_run[r] = l_run[r] * fac[r] + ps[r];
        #pragma unroll
        for (int c = 0; c < 4; ++c) {
            #pragma unroll
            for (int r = 0; r < 4; ++r) o[c][r] *= fac[r];
        }

        // ---- P -> per-wave LDS (A-fragment layout source) ----
        #pragma unroll
        for (int n = 0; n < 4; ++n) {
            #pragma unroll
            for (int r = 0; r < 4; ++r) {
                const int ql = 4 * l4 + r;
                const int kv = 16 * n + l15;
                *(unsigned short*)(pwb + ql * 128 + ((2 * kv) ^ ((ql & 7) << 4))) = pb[n][r];
            }
        }

        // ---- O += P V ----
        #pragma unroll
        for (int hh = 0; hh < 2; ++hh) {
            const int kb0 = 32 * hh + 8 * l4;
            bf16x8 pa = *(const bf16x8*)(pwb + l15 * 128 + ((2 * kb0) ^ ((l15 & 7) << 4)));
            #pragma unroll
            for (int c = 0; c < 4; ++c) {
                const int erow = 16 * c + l15;
                bf16x8 vb = *(const bf16x8*)(vt_base + erow * 128 + ((2 * kb0) ^ ((erow & 7) << 4)));
                o[c] = __builtin_amdgcn_mfma_f32_16x16x32_bf16(pa, vb, o[c], 0, 0, 0);
            }
        }
    }

    // ---- epilogue: normalize and store fp32 ----
    float inv[4];
    #pragma unroll
    for (int r = 0; r < 4; ++r) inv[r] = 1.f / l_run[r];
    float* op = Out + base_bh;
    #pragma unroll
    for (int c = 0; c < 4; ++c) {
        #pragma unroll
        for (int r = 0; r < 4; ++r) {
            const int q_g = qrow0 + 4 * l4 + r;
            op[(size_t)q_g * strideL + 16 * c + l15] = o[c][r] * inv[r];
        }
    }
}

extern "C" void kernel_launch(void* const* d_in, const int* in_sizes, int n_in,
                              void* d_out, int out_size, void* d_ws, size_t ws_size,
                              hipStream_t stream) {
    const float* Q = (const float*)d_in[0];
    const float* K = (const float*)d_in[1];
    const float* V = (const float*)d_in[2];
    float* O = (float*)d_out;
    dim3 grid((Lc / QBLK) * Bc * Hc);   // 32 q-tiles * 32 (b,h) = 1024 blocks
    dim3 block(256);
    hipLaunchKernelGGL(fa_fwd_kernel, grid, block, 0, stream, Q, K, V, O);
}

// Round 3
// 67.348 us; speedup vs baseline: 1.5996x; 1.5996x over previous
//
#include <hip/hip_runtime.h>
#include <hip/hip_bf16.h>

// Causal flash-attention forward. B=4, L=2048, H=8, E=64, fp32 in/out.
// Layout: [B, L, H, E] -> ((b*L + l)*H + h)*E + e ; row stride H*E = 512 floats.
//
// Structure: prepass converts K and V^T to f16 "LDS-image" tiles (XOR-swizzled,
// byte ^= (row&7)<<4) in d_ws; main kernel double-buffers them in via
// global_load_lds(16B) and computes swapped QK^T (S^T = K·Q^T) so P stays
// lane-local and feeds mfma_f32_16x16x16f16 A-fragments directly (no P LDS).

#define Bc 4
#define Lc 2048
#define Hc 8
#define Ec 64
#define TB 64
#define NT (Lc / TB)                   // 32 tiles
// ws layout: K images [32 bh][32 kt][8192 B], then V^T images same, total 16 MB.
#define BH_BYTES (NT * TB * Ec * 2)    // 262144
#define WS_V_OFF ((size_t)32 * BH_BYTES)

using f32x4 = __attribute__((ext_vector_type(4))) float;
using f16x8 = __attribute__((ext_vector_type(8))) _Float16;
using f16x4 = __attribute__((ext_vector_type(4))) _Float16;
using hf16x2 = __fp16 __attribute__((ext_vector_type(2)));   // cvt_pkrtz native type

static __device__ __forceinline__ unsigned int pk2(float lo, float hi) {
    union { hf16x2 h; unsigned int u; } c;
    c.h = __builtin_amdgcn_cvt_pkrtz(lo, hi);
    return c.u;
}

static __device__ __forceinline__ void gload16(const void* g, void* l) {
    __builtin_amdgcn_global_load_lds(
        (const __attribute__((address_space(1))) unsigned int*)g,
        (__attribute__((address_space(3))) unsigned int*)l, 16, 0, 0);
}

// ---------------- prepass: fp32 -> f16 swizzled tile images ----------------
__global__ __launch_bounds__(256)
void prep_kernel(const float* __restrict__ K, const float* __restrict__ V,
                 char* __restrict__ ws)
{
    __shared__ char vstage[64 * 144];   // [kv][72 f16], 144B row stride (pad)

    const int bid = blockIdx.x;
    const int bh = bid >> 5, kt = bid & 31;
    const int b = bh >> 3, h = bh & 7;
    const int tid = threadIdx.x;
    const int r = tid >> 2, q4 = tid & 3;
    const int c0 = 16 * q4;
    const size_t base_bh = (size_t)b * Lc * Hc * Ec + (size_t)h * Ec;
    const int kbase = kt * TB;
    char* kimg = ws + (size_t)bh * BH_BYTES + (size_t)kt * 8192;
    char* vimg = ws + WS_V_OFF + (size_t)bh * BH_BYTES + (size_t)kt * 8192;

    const int rs = (r & 7) << 4;
    {   // K tile: row-major [kv][e], swizzled
        const float* kp = K + base_bh + (size_t)(kbase + r) * 512 + c0;
        unsigned int w[8];
        #pragma unroll
        for (int i = 0; i < 4; ++i) {
            float4 f = *(const float4*)(kp + 4 * i);
            w[2*i]   = pk2(f.x, f.y);
            w[2*i+1] = pk2(f.z, f.w);
        }
        *(uint4*)(kimg + r * 128 + ((32*q4)      ^ rs)) = *(uint4*)&w[0];
        *(uint4*)(kimg + r * 128 + ((32*q4 + 16) ^ rs)) = *(uint4*)&w[4];
    }
    {   // V tile -> LDS (row-major, padded)
        const float* vp = V + base_bh + (size_t)(kbase + r) * 512 + c0;
        unsigned int w[8];
        #pragma unroll
        for (int i = 0; i < 4; ++i) {
            float4 f = *(const float4*)(vp + 4 * i);
            w[2*i]   = pk2(f.x, f.y);
            w[2*i+1] = pk2(f.z, f.w);
        }
        *(uint4*)(vstage + r * 144 + 32*q4)      = *(uint4*)&w[0];
        *(uint4*)(vstage + r * 144 + 32*q4 + 16) = *(uint4*)&w[4];
    }
    __syncthreads();
    {   // transpose: V^T tile rows e, cols kv, swizzled
        const int e = tid >> 2, kq = tid & 3, kv0 = 16 * kq;
        unsigned int w[8];
        #pragma unroll
        for (int i = 0; i < 8; ++i) {
            unsigned int lo = *(const unsigned short*)(vstage + (kv0 + 2*i)     * 144 + 2*e);
            unsigned int hi = *(const unsigned short*)(vstage + (kv0 + 2*i + 1) * 144 + 2*e);
            w[i] = lo | (hi << 16);
        }
        const int es = (e & 7) << 4;
        *(uint4*)(vimg + e * 128 + ((32*kq)      ^ es)) = *(uint4*)&w[0];
        *(uint4*)(vimg + e * 128 + ((32*kq + 16) ^ es)) = *(uint4*)&w[4];
    }
}

// ---------------- main kernel ----------------
__global__ __launch_bounds__(256)
void fa_fwd_kernel(const float* __restrict__ Q, const char* __restrict__ ws,
                   float* __restrict__ Out)
{
    __shared__ char klds[2 * 8192];
    __shared__ char vlds[2 * 8192];

    const int bid = blockIdx.x;
    const int qi  = bid >> 5;
    const int bh  = bid & 31;
    const int b   = bh >> 3, h = bh & 7;
    const int qt  = (NT - 1) - qi;          // longest-running tiles first
    const int qbase = qt * TB;

    const int tid  = threadIdx.x;
    const int wid  = tid >> 6;
    const int lane = tid & 63;
    const int l15  = lane & 15;
    const int l4   = lane >> 4;

    const size_t base_bh = (size_t)b * Lc * Hc * Ec + (size_t)h * Ec;
    const char* kimg = ws + (size_t)bh * BH_BYTES;
    const char* vimg = ws + WS_V_OFF + (size_t)bh * BH_BYTES;

    // Q fragment (B-operand): lane holds Q[q = qrow0 + l15][k = 32*kc + 8*l4 + j]
    const int qrow0 = qbase + 16 * wid;
    f16x8 qa[2];
    {
        const float* qpr = Q + base_bh + (size_t)(qrow0 + l15) * 512;
        #pragma unroll
        for (int kc = 0; kc < 2; ++kc) {
            const float* p = qpr + 32 * kc + 8 * l4;
            float4 f0 = *(const float4*)(p);
            float4 f1 = *(const float4*)(p + 4);
            union { f16x8 v; unsigned int u[4]; } pk;
            pk.u[0] = pk2(f0.x, f0.y);
            pk.u[1] = pk2(f0.z, f0.w);
            pk.u[2] = pk2(f1.x, f1.y);
            pk.u[3] = pk2(f1.z, f1.w);
            qa[kc] = pk.v;
        }
    }

    f32x4 o[4] = {};                         // O acc: row q=4*l4+reg, col e=16c+l15
    float m_run = -1e30f, l_run = 0.f;       // stats live in q = l15 domain
    const float SL2E = 0.125f * 1.44269504088896340736f;

    const int stoff = wid * 2048 + lane * 16;   // wave-uniform base + lane*16
    gload16(kimg + stoff,        klds + stoff);
    gload16(kimg + stoff + 1024, klds + stoff + 1024);
    gload16(vimg + stoff,        vlds + stoff);
    gload16(vimg + stoff + 1024, vlds + stoff + 1024);
    __syncthreads();

    for (int kt = 0; kt <= qt; ++kt) {
        const int cur = kt & 1;
        const char* kb = klds + cur * 8192;
        const char* vb = vlds + cur * 8192;

        if (kt < qt) {   // issue next-tile stage before compute (T3 2-phase)
            const char* ks = kimg + (size_t)(kt + 1) * 8192;
            const char* vs = vimg + (size_t)(kt + 1) * 8192;
            char* kd = klds + (cur ^ 1) * 8192;
            char* vd = vlds + (cur ^ 1) * 8192;
            gload16(ks + stoff,        kd + stoff);
            gload16(ks + stoff + 1024, kd + stoff + 1024);
            gload16(vs + stoff,        vd + stoff);
            gload16(vs + stoff + 1024, vd + stoff + 1024);
        }

        // S^T = K·Q^T : lane holds S[kv = kbase+16n+4*l4+r][q = qrow0+l15]
        f32x4 s[4];
        #pragma unroll
        for (int n = 0; n < 4; ++n) {
            const int row = 16 * n + l15;
            const int rsw = (row & 7) << 4;
            f16x8 a0 = *(const f16x8*)(kb + row * 128 + ((16 * l4)      ^ rsw));
            f16x8 a1 = *(const f16x8*)(kb + row * 128 + ((64 + 16 * l4) ^ rsw));
            f32x4 z = {0.f, 0.f, 0.f, 0.f};
            z = __builtin_amdgcn_mfma_f32_16x16x32_f16(a0, qa[0], z, 0, 0, 0);
            z = __builtin_amdgcn_mfma_f32_16x16x32_f16(a1, qa[1], z, 0, 0, 0);
            s[n] = z;
        }

        if (kt == qt) {   // causal mask on the diagonal tile
            const int q_g = qrow0 + l15;
            #pragma unroll
            for (int n = 0; n < 4; ++n) {
                #pragma unroll
                for (int r = 0; r < 4; ++r) {
                    const int kv_g = kt * TB + 16 * n + 4 * l4 + r;
                    if (kv_g > q_g) s[n][r] = -1e30f;
                }
            }
        }

        // online softmax (scalar stats per q-column)
        float pmax = -1e30f;
        #pragma unroll
        for (int n = 0; n < 4; ++n)
            #pragma unroll
            for (int r = 0; r < 4; ++r) pmax = fmaxf(pmax, s[n][r]);
        pmax = fmaxf(pmax, __shfl_xor(pmax, 16, 64));
        pmax = fmaxf(pmax, __shfl_xor(pmax, 32, 64));
        const float m_new = fmaxf(m_run, pmax);
        const float fac = __builtin_exp2f((m_run - m_new) * SL2E);
        m_run = m_new;

        float ps = 0.f;
        unsigned int ph[4][2];
        #pragma unroll
        for (int n = 0; n < 4; ++n) {
            float p0 = __builtin_exp2f((s[n][0] - m_new) * SL2E);
            float p1 = __builtin_exp2f((s[n][1] - m_new) * SL2E);
            float p2 = __builtin_exp2f((s[n][2] - m_new) * SL2E);
            float p3 = __builtin_exp2f((s[n][3] - m_new) * SL2E);
            ps += (p0 + p1) + (p2 + p3);
            ph[n][0] = pk2(p0, p1);
            ph[n][1] = pk2(p2, p3);
        }
        ps += __shfl_xor(ps, 16, 64);
        ps += __shfl_xor(ps, 32, 64);
        l_run = l_run * fac + ps;

        // move fac from q=l15 domain to o-row domain (q = 4*l4+r)
        float fr[4];
        #pragma unroll
        for (int r = 0; r < 4; ++r) fr[r] = __shfl(fac, 20 * l4 + r, 64);
        #pragma unroll
        for (int c = 0; c < 4; ++c)
            #pragma unroll
            for (int r = 0; r < 4; ++r) o[c][r] *= fr[r];

        // O += P·V : P is already in A-frag layout for 16x16x16 (k = 4*l4 + j)
        #pragma unroll
        for (int m = 0; m < 4; ++m) {
            union { f16x4 h; unsigned int u[2]; } pa;
            pa.u[0] = ph[m][0]; pa.u[1] = ph[m][1];
            #pragma unroll
            for (int c = 0; c < 4; ++c) {
                const int erow = 16 * c + l15;
                const f16x4 vbf = *(const f16x4*)(vb + erow * 128 +
                                   ((32 * m + 8 * l4) ^ ((erow & 7) << 4)));
                o[c] = __builtin_amdgcn_mfma_f32_16x16x16f16(pa.h, vbf, o[c], 0, 0, 0);
            }
        }
        __syncthreads();   // drains vmcnt(0)+lgkmcnt(0): next tile staged & reads done
    }

    // epilogue: normalize (1/l from q=l15 domain) and store fp32
    const float inv = 1.f / l_run;
    float ir[4];
    #pragma unroll
    for (int r = 0; r < 4; ++r) ir[r] = __shfl(inv, 20 * l4 + r, 64);
    float* op = Out + base_bh;
    #pragma unroll
    for (int c = 0; c < 4; ++c)
        #pragma unroll
        for (int r = 0; r < 4; ++r)
            op[(size_t)(qrow0 + 4 * l4 + r) * 512 + 16 * c + l15] = o[c][r] * ir[r];
}

extern "C" void kernel_launch(void* const* d_in, const int* in_sizes, int n_in,
                              void* d_out, int out_size, void* d_ws, size_t ws_size,
                              hipStream_t stream) {
    const float* Q = (const float*)d_in[0];
    const float* K = (const float*)d_in[1];
    const float* V = (const float*)d_in[2];
    float* O = (float*)d_out;
    char* ws = (char*)d_ws;   // needs 16 MB (2 x 8 MB f16 tile images)
    hipLaunchKernelGGL(prep_kernel, dim3(Bc * Hc * NT), dim3(256), 0, stream, K, V, ws);
    hipLaunchKernelGGL(fa_fwd_kernel, dim3(NT * Bc * Hc), dim3(256), 0, stream, Q, ws, O);
}

// Round 4
// 65.504 us; speedup vs baseline: 1.6446x; 1.0282x over previous
//
#include <hip/hip_runtime.h>
#include <hip/hip_bf16.h>

// Causal flash-attention forward. B=4, L=2048, H=8, E=64, fp32 in/out.
// Layout: [B, L, H, E] -> ((b*L + l)*H + h)*E + e ; row stride H*E = 512 floats.
//
// prepass: K and V^T -> f16 swizzled LDS-image tiles in d_ws.
// main: paired q-tiles (qt, 31-qt) per block (33 steps each, perfect balance),
// double-buffered global_load_lds staging, swapped QK^T (S^T = K·Q^T) so P is
// lane-local and feeds mfma_f32_16x16x16f16 directly; row-sum l via ones-column
// MFMA; defer-max rescale skipping (THR=8 in exp2 domain).

#define Bc 4
#define Lc 2048
#define Hc 8
#define Ec 64
#define TB 64
#define NT (Lc / TB)                   // 32 tiles
#define BH_BYTES (NT * TB * Ec * 2)    // 262144
#define WS_V_OFF ((size_t)32 * BH_BYTES)

using f32x4 = __attribute__((ext_vector_type(4))) float;
using f16x8 = __attribute__((ext_vector_type(8))) _Float16;
using f16x4 = __attribute__((ext_vector_type(4))) _Float16;
using hf16x2 = __fp16 __attribute__((ext_vector_type(2)));   // cvt_pkrtz native type

static __device__ __forceinline__ unsigned int pk2(float lo, float hi) {
    union { hf16x2 h; unsigned int u; } c;
    c.h = __builtin_amdgcn_cvt_pkrtz(lo, hi);
    return c.u;
}

static __device__ __forceinline__ void gload16(const void* g, void* l) {
    __builtin_amdgcn_global_load_lds(
        (const __attribute__((address_space(1))) unsigned int*)g,
        (__attribute__((address_space(3))) unsigned int*)l, 16, 0, 0);
}

// ---------------- prepass: fp32 -> f16 swizzled tile images ----------------
__global__ __launch_bounds__(256)
void prep_kernel(const float* __restrict__ K, const float* __restrict__ V,
                 char* __restrict__ ws)
{
    __shared__ char vstage[64 * 144];   // [kv][72 f16], padded row

    const int bid = blockIdx.x;
    const int bh = bid >> 5, kt = bid & 31;
    const int b = bh >> 3, h = bh & 7;
    const int tid = threadIdx.x;
    const int r = tid >> 2, q4 = tid & 3;
    const int c0 = 16 * q4;
    const size_t base_bh = (size_t)b * Lc * Hc * Ec + (size_t)h * Ec;
    const int kbase = kt * TB;
    char* kimg = ws + (size_t)bh * BH_BYTES + (size_t)kt * 8192;
    char* vimg = ws + WS_V_OFF + (size_t)bh * BH_BYTES + (size_t)kt * 8192;

    const int rs = (r & 7) << 4;
    {   // K tile: row-major [kv][e], swizzled
        const float* kp = K + base_bh + (size_t)(kbase + r) * 512 + c0;
        unsigned int w[8];
        #pragma unroll
        for (int i = 0; i < 4; ++i) {
            float4 f = *(const float4*)(kp + 4 * i);
            w[2*i]   = pk2(f.x, f.y);
            w[2*i+1] = pk2(f.z, f.w);
        }
        *(uint4*)(kimg + r * 128 + ((32*q4)      ^ rs)) = *(uint4*)&w[0];
        *(uint4*)(kimg + r * 128 + ((32*q4 + 16) ^ rs)) = *(uint4*)&w[4];
    }
    {   // V tile -> LDS row-major (padded)
        const float* vp = V + base_bh + (size_t)(kbase + r) * 512 + c0;
        unsigned int w[8];
        #pragma unroll
        for (int i = 0; i < 4; ++i) {
            float4 f = *(const float4*)(vp + 4 * i);
            w[2*i]   = pk2(f.x, f.y);
            w[2*i+1] = pk2(f.z, f.w);
        }
        *(uint4*)(vstage + r * 144 + 32*q4)      = *(uint4*)&w[0];
        *(uint4*)(vstage + r * 144 + 32*q4 + 16) = *(uint4*)&w[4];
    }
    __syncthreads();
    {   // transpose: V^T rows e, cols kv, swizzled
        const int e = tid >> 2, kq = tid & 3, kv0 = 16 * kq;
        unsigned int w[8];
        #pragma unroll
        for (int i = 0; i < 8; ++i) {
            unsigned int lo = *(const unsigned short*)(vstage + (kv0 + 2*i)     * 144 + 2*e);
            unsigned int hi = *(const unsigned short*)(vstage + (kv0 + 2*i + 1) * 144 + 2*e);
            w[i] = lo | (hi << 16);
        }
        const int es = (e & 7) << 4;
        *(uint4*)(vimg + e * 128 + ((32*kq)      ^ es)) = *(uint4*)&w[0];
        *(uint4*)(vimg + e * 128 + ((32*kq + 16) ^ es)) = *(uint4*)&w[4];
    }
}

// ---------------- main kernel ----------------
__global__ __launch_bounds__(256)
void fa_fwd_kernel(const float* __restrict__ Q, const char* __restrict__ ws,
                   float* __restrict__ Out)
{
    __shared__ char klds[2 * 8192];
    __shared__ char vlds[2 * 8192];

    const int bid = blockIdx.x;
    const int pi  = bid >> 5;               // 0..15 pair index
    const int bh  = bid & 31;
    const int b   = bh >> 3, h = bh & 7;

    const int tid  = threadIdx.x;
    const int wid  = tid >> 6;
    const int lane = tid & 63;
    const int l15  = lane & 15;
    const int l4   = lane >> 4;

    const size_t base_bh = (size_t)b * Lc * Hc * Ec + (size_t)h * Ec;
    const char* kimg = ws + (size_t)bh * BH_BYTES;
    const char* vimg = ws + WS_V_OFF + (size_t)bh * BH_BYTES;
    const float SL2E = 0.125f * 1.44269504088896340736f;

    // loop-invariant swizzled LDS read offsets (row&7 == l15&7 throughout)
    const int sw  = (l15 & 7) << 4;
    const int ko0 = l15 * 128 + ((16 * l4)      ^ sw);
    const int ko1 = l15 * 128 + ((64 + 16 * l4) ^ sw);
    int vo[4];
    #pragma unroll
    for (int m = 0; m < 4; ++m) vo[m] = l15 * 128 + ((32 * m + 8 * l4) ^ sw);

    // constant ones B-fragment: B[k][0]=1 else 0 -> row-sum column
    f16x4 ones;
    {
        const _Float16 ov = (_Float16)((l15 == 0) ? 1.0f : 0.0f);
        ones[0] = ov; ones[1] = ov; ones[2] = ov; ones[3] = ov;
    }

    const int stoff = wid * 2048 + lane * 16;

    #pragma unroll 1
    for (int half = 0; half < 2; ++half) {
        const int qt = half ? pi : (NT - 1 - pi);
        const int qrow0 = qt * TB + 16 * wid;

        // Q fragment (B-operand), prescaled by scale*log2(e)
        f16x8 qa0, qa1;
        {
            const float* qpr = Q + base_bh + (size_t)(qrow0 + l15) * 512 + 8 * l4;
            float4 f0 = *(const float4*)(qpr);
            float4 f1 = *(const float4*)(qpr + 4);
            float4 f2 = *(const float4*)(qpr + 32);
            float4 f3 = *(const float4*)(qpr + 36);
            union { f16x8 v; unsigned int u[4]; } pk;
            pk.u[0] = pk2(f0.x * SL2E, f0.y * SL2E);
            pk.u[1] = pk2(f0.z * SL2E, f0.w * SL2E);
            pk.u[2] = pk2(f1.x * SL2E, f1.y * SL2E);
            pk.u[3] = pk2(f1.z * SL2E, f1.w * SL2E);
            qa0 = pk.v;
            pk.u[0] = pk2(f2.x * SL2E, f2.y * SL2E);
            pk.u[1] = pk2(f2.z * SL2E, f2.w * SL2E);
            pk.u[2] = pk2(f3.x * SL2E, f3.y * SL2E);
            pk.u[3] = pk2(f3.z * SL2E, f3.w * SL2E);
            qa1 = pk.v;
        }

        f32x4 o[4] = {};
        f32x4 ol = {};                 // row-sum (l) accumulator, col 0
        float m_run = -1e30f;

        // stage tile 0 of this half
        gload16(kimg + stoff,        klds + stoff);
        gload16(kimg + stoff + 1024, klds + stoff + 1024);
        gload16(vimg + stoff,        vlds + stoff);
        gload16(vimg + stoff + 1024, vlds + stoff + 1024);
        __syncthreads();

        for (int kt = 0; kt <= qt; ++kt) {
            const int cur = kt & 1;
            const char* kb = klds + cur * 8192;
            const char* vb = vlds + cur * 8192;

            if (kt < qt) {   // prefetch next tile into other buffer
                const char* ks = kimg + (size_t)(kt + 1) * 8192;
                const char* vs = vimg + (size_t)(kt + 1) * 8192;
                char* kd = klds + (cur ^ 1) * 8192;
                char* vd = vlds + (cur ^ 1) * 8192;
                gload16(ks + stoff,        kd + stoff);
                gload16(ks + stoff + 1024, kd + stoff + 1024);
                gload16(vs + stoff,        vd + stoff);
                gload16(vs + stoff + 1024, vd + stoff + 1024);
            }

            // S^T = K·Q^T : lane holds S[kv=16n+4*l4+r][q=qrow0+l15] (exp2 units)
            f32x4 s[4];
            #pragma unroll
            for (int n = 0; n < 4; ++n) {
                f16x8 a0 = *(const f16x8*)(kb + n * 2048 + ko0);
                f16x8 a1 = *(const f16x8*)(kb + n * 2048 + ko1);
                f32x4 z = {0.f, 0.f, 0.f, 0.f};
                z = __builtin_amdgcn_mfma_f32_16x16x32_f16(a0, qa0, z, 0, 0, 0);
                z = __builtin_amdgcn_mfma_f32_16x16x32_f16(a1, qa1, z, 0, 0, 0);
                s[n] = z;
            }

            if (kt == qt) {   // causal mask on the diagonal tile
                const int q_g = qrow0 + l15;
                #pragma unroll
                for (int n = 0; n < 4; ++n) {
                    #pragma unroll
                    for (int r = 0; r < 4; ++r) {
                        const int kv_g = kt * TB + 16 * n + 4 * l4 + r;
                        if (kv_g > q_g) s[n][r] = -1e30f;
                    }
                }
            }

            // col max (binary tree; clang fuses to v_max3)
            float a0 = fmaxf(s[0][0], s[0][1]), a1 = fmaxf(s[0][2], s[0][3]);
            float a2 = fmaxf(s[1][0], s[1][1]), a3 = fmaxf(s[1][2], s[1][3]);
            float a4 = fmaxf(s[2][0], s[2][1]), a5 = fmaxf(s[2][2], s[2][3]);
            float a6 = fmaxf(s[3][0], s[3][1]), a7 = fmaxf(s[3][2], s[3][3]);
            float pmax = fmaxf(fmaxf(fmaxf(a0, a1), fmaxf(a2, a3)),
                               fmaxf(fmaxf(a4, a5), fmaxf(a6, a7)));
            pmax = fmaxf(pmax, __shfl_xor(pmax, 16, 64));
            pmax = fmaxf(pmax, __shfl_xor(pmax, 32, 64));

            // defer-max: only rescale when the new max grew past THR=8
            if (!__all(pmax - m_run <= 8.0f)) {
                const float m_new = fmaxf(m_run, pmax);
                const float fac = __builtin_exp2f(m_run - m_new);
                m_run = m_new;
                float fr[4];
                #pragma unroll
                for (int r = 0; r < 4; ++r) fr[r] = __shfl(fac, 4 * l4 + r, 64);
                #pragma unroll
                for (int c = 0; c < 4; ++c)
                    #pragma unroll
                    for (int r = 0; r < 4; ++r) o[c][r] *= fr[r];
                #pragma unroll
                for (int r = 0; r < 4; ++r) ol[r] *= fr[r];
            }

            // P = exp2(s - m_run), packed f16
            unsigned int ph[4][2];
            #pragma unroll
            for (int n = 0; n < 4; ++n) {
                float p0 = __builtin_exp2f(s[n][0] - m_run);
                float p1 = __builtin_exp2f(s[n][1] - m_run);
                float p2 = __builtin_exp2f(s[n][2] - m_run);
                float p3 = __builtin_exp2f(s[n][3] - m_run);
                ph[n][0] = pk2(p0, p1);
                ph[n][1] = pk2(p2, p3);
            }

            // O += P·V and l += P·1 (ones-column MFMA)
            #pragma unroll
            for (int m = 0; m < 4; ++m) {
                union { f16x4 h; unsigned int u[2]; } pa;
                pa.u[0] = ph[m][0]; pa.u[1] = ph[m][1];
                ol = __builtin_amdgcn_mfma_f32_16x16x16f16(pa.h, ones, ol, 0, 0, 0);
                #pragma unroll
                for (int c = 0; c < 4; ++c) {
                    const f16x4 vbf = *(const f16x4*)(vb + c * 2048 + vo[m]);
                    o[c] = __builtin_amdgcn_mfma_f32_16x16x16f16(pa.h, vbf, o[c], 0, 0, 0);
                }
            }
            __syncthreads();   // drains vmcnt/lgkmcnt: prefetch landed, reads done
        }

        // epilogue: normalize by l (col 0 of ol, lanes l15==0) and store
        float ir[4];
        #pragma unroll
        for (int r = 0; r < 4; ++r) {
            const float iv = 1.0f / ol[r];
            ir[r] = __shfl(iv, 16 * l4, 64);   // broadcast from l15==0 lane
        }
        float* op = Out + base_bh;
        #pragma unroll
        for (int c = 0; c < 4; ++c)
            #pragma unroll
            for (int r = 0; r < 4; ++r)
                op[(size_t)(qrow0 + 4 * l4 + r) * 512 + 16 * c + l15] = o[c][r] * ir[r];
    }
}

extern "C" void kernel_launch(void* const* d_in, const int* in_sizes, int n_in,
                              void* d_out, int out_size, void* d_ws, size_t ws_size,
                              hipStream_t stream) {
    const float* Q = (const float*)d_in[0];
    const float* K = (const float*)d_in[1];
    const float* V = (const float*)d_in[2];
    float* O = (float*)d_out;
    char* ws = (char*)d_ws;   // 16 MB tile images
    hipLaunchKernelGGL(prep_kernel, dim3(Bc * Hc * NT), dim3(256), 0, stream, K, V, ws);
    hipLaunchKernelGGL(fa_fwd_kernel, dim3((NT / 2) * Bc * Hc), dim3(256), 0, stream, Q, ws, O);
}